// Round 11
// baseline (32.876 us; speedup 1.0000x reference)
//
#include <hip/hip_runtime.h>

#define NB   384
#define ND   256
#define NBIN 384

// ws float offsets
#define WF_OFF   0        // wf[4] = tw_t / count_t
#define TICK_OFF 8        // unsigned ticket counter (memset to 0 per launch)
#define PART_OFF 16       // partial[384]
#define G_OFF    512      // G[384][384] = E E^T

// ---------------------------------------------------------------------------
// K1: Gram matrix G = E E^T, f32 LDS-tiled GEMM. 144 blocks = 12x12 tiles of
// 32x32, 256 threads, 2x2 outputs/thread. Block 0 also computes wf[4].
// Distances later derive as d^2 = G_ii + G_pp - 2 G_ip  (exact-enough f32).
// ---------------------------------------------------------------------------
__global__ __launch_bounds__(256) void gram_kernel(
    const float* __restrict__ emb,
    const float* __restrict__ tw,
    const int*   __restrict__ rank,
    float* __restrict__ ws)
{
    __shared__ float As[32][70];     // pad 70: 8B-aligned rows, 2-way banks max
    __shared__ float Bs[32][70];
    __shared__ unsigned hist[20];

    const int tid  = threadIdx.x;
    const int bi   = blockIdx.x % 12;
    const int bj   = blockIdx.x / 12;
    const int tx   = tid & 15, ty = tid >> 4;
    const int srow = tid >> 3, scol = (tid & 7) * 8;

    float a00 = 0.f, a01 = 0.f, a10 = 0.f, a11 = 0.f;
    for (int kc = 0; kc < ND; kc += 64) {
        const float2* pa = reinterpret_cast<const float2*>(
            emb + (size_t)(bi * 32 + srow) * ND + kc + scol);
        const float2* pb = reinterpret_cast<const float2*>(
            emb + (size_t)(bj * 32 + srow) * ND + kc + scol);
        float2 va0 = pa[0], va1 = pa[1], va2 = pa[2], va3 = pa[3];
        float2 vb0 = pb[0], vb1 = pb[1], vb2 = pb[2], vb3 = pb[3];
        *reinterpret_cast<float2*>(&As[srow][scol + 0]) = va0;
        *reinterpret_cast<float2*>(&As[srow][scol + 2]) = va1;
        *reinterpret_cast<float2*>(&As[srow][scol + 4]) = va2;
        *reinterpret_cast<float2*>(&As[srow][scol + 6]) = va3;
        *reinterpret_cast<float2*>(&Bs[srow][scol + 0]) = vb0;
        *reinterpret_cast<float2*>(&Bs[srow][scol + 2]) = vb1;
        *reinterpret_cast<float2*>(&Bs[srow][scol + 4]) = vb2;
        *reinterpret_cast<float2*>(&Bs[srow][scol + 6]) = vb3;
        __syncthreads();
        #pragma unroll 8
        for (int k = 0; k < 64; ++k) {
            const float A0 = As[ty * 2][k],     A1 = As[ty * 2 + 1][k];
            const float B0 = Bs[tx * 2][k],     B1 = Bs[tx * 2 + 1][k];
            a00 = fmaf(A0, B0, a00);
            a01 = fmaf(A0, B1, a01);
            a10 = fmaf(A1, B0, a10);
            a11 = fmaf(A1, B1, a11);
        }
        __syncthreads();
    }
    float* G = ws + G_OFF;
    const int r = bi * 32 + ty * 2, c = bj * 32 + tx * 2;
    float2 s0; s0.x = a00; s0.y = a01;
    float2 s1; s1.x = a10; s1.y = a11;
    *reinterpret_cast<float2*>(&G[(size_t)r * NB + c])       = s0;
    *reinterpret_cast<float2*>(&G[(size_t)(r + 1) * NB + c]) = s1;

    if (blockIdx.x == 0) {
        if (tid < 20) hist[tid] = 0u;
        __syncthreads();
        for (int e = tid; e < NB * 4; e += 256)
            atomicAdd(&hist[(e & 3) * 5 + rank[e]], 1u);
        __syncthreads();
        if (tid < 4) {
            double cnt = 0.0;
            unsigned below = 0;
            #pragma unroll
            for (int v = 0; v < 5; ++v) {
                unsigned hv = hist[tid * 5 + v];
                unsigned above = (unsigned)NB - below - hv;
                cnt += (double)hv * (double)below * (double)above;
                below += hv;
            }
            ws[WF_OFF + tid] = (cnt > 0.0) ? (float)((double)tw[tid] / cnt) : 0.f;
        }
    }
}

// ---------------------------------------------------------------------------
// K2: one block per row i, 384 threads (thread p == element p, no pads).
//  P0: d_p = sqrt(max(G_ii + G_pp - 2 G_ip, 0))    [2 coalesced + 1 diag load]
//  P2: min (excl. self) / max -> integer bins-per-unit S; bin(d+1)=bin(d)+S
//  P3: 384-bin histogram -> shfl prefix scan -> counting scatter of rank packs
//  P4: ballot cumulative-rank masks over d-grouped order
//  P5: j-role/k-role counts at bin-boundary cuts (pair sets identical by
//      construction); contribution = jacc*(d+1) - kacc*d
//  Tail: partial -> release store; acq-rel ticket; LAST block reduces -> out.
// ---------------------------------------------------------------------------
__global__ __launch_bounds__(NB) void loss_kernel(
    const float* __restrict__ G,
    const int*   __restrict__ rank,
    const float* __restrict__ wf,
    float*       __restrict__ partial,
    unsigned*    __restrict__ tick,
    float*       __restrict__ out)
{
    __shared__ unsigned hist[NBIN];
    __shared__ unsigned offs[NBIN + 1];
    __shared__ unsigned curs[NBIN];
    __shared__ unsigned srk[NB];
    __shared__ unsigned long long cm[7][16];   // row 6: zero (P==384 overread)
    __shared__ unsigned cumtab[7][16];         // row 6: grand totals
    __shared__ unsigned wtot[6];
    __shared__ float    mmx[12];
    __shared__ float    sprm[2];
    __shared__ float    wfl[4];
    __shared__ float    red[6];
    __shared__ int      lastflag;

    const int p  = threadIdx.x;        // 0..383
    const int bi = blockIdx.x;
    const int wv = p >> 6;             // 0..5

    if (p < 4)  wfl[p] = wf[p];
    if (p < 16) cm[6][p] = 0ull;
    hist[p] = 0u;

    // P0: distance from Gram row
    const float ni  = G[(size_t)bi * NB + bi];          // uniform -> scalar
    const float g   = G[(size_t)bi * NB + p];           // coalesced
    const float npp = G[(size_t)p * (NB + 1)];          // diagonal (scattered)
    const float d   = sqrtf(fmaxf(ni + npp - 2.f * g, 0.f));

    // P2: min (excluding self) / max -> scale
    float dl = (p == bi) ? 3.0e38f : d;
    float dh = d;
    #pragma unroll
    for (int off = 32; off > 0; off >>= 1) {
        dl = fminf(dl, __shfl_xor(dl, off, 64));
        dh = fmaxf(dh, __shfl_xor(dh, off, 64));
    }
    if ((p & 63) == 0) { mmx[wv] = dl; mmx[6 + wv] = dh; }
    __syncthreads();
    if (p == 0) {
        float mn = mmx[0], mx = mmx[6];
        #pragma unroll
        for (int w = 1; w < 6; ++w) {
            mn = fminf(mn, mmx[w]);
            mx = fmaxf(mx, mmx[6 + w]);
        }
        int S = (int)(383.0f / (mx - mn + 1.0f));
        if (S < 1) S = 1;
        sprm[0] = mn;
        sprm[1] = (float)S;
    }
    __syncthreads();
    const float dmin   = sprm[0];
    const float scaleF = sprm[1];
    const int   S      = (int)scaleF;

    // P3a: histogram (q clamped; self-distance lands in bin 0, rank-excluded)
    int q = (int)((d - dmin) * scaleF);
    if (q < 0) q = 0;
    if (q > NBIN - 1) q = NBIN - 1;
    atomicAdd(&hist[q], 1u);
    const int4 r4 = *reinterpret_cast<const int4*>(rank + p * 4);
    const unsigned rpk = (unsigned)r4.x | ((unsigned)r4.y << 8) |
                         ((unsigned)r4.z << 16) | ((unsigned)r4.w << 24);
    __syncthreads();

    // P3b: exclusive prefix over 384 bins
    const unsigned h = hist[p];
    unsigned inc = h;
    #pragma unroll
    for (int s = 1; s < 64; s <<= 1) {
        const unsigned o = __shfl_up(inc, s, 64);
        if ((p & 63) >= s) inc += o;
    }
    if ((p & 63) == 63) wtot[wv] = inc;
    __syncthreads();
    unsigned woff = 0;
    for (int w = 0; w < wv; ++w) woff += wtot[w];
    const unsigned excl = woff + inc - h;
    offs[p] = excl;
    curs[p] = excl;
    if (p == NBIN - 1) offs[NBIN] = excl + h;   // == NB
    __syncthreads();

    // P3c: counting scatter into d-grouped order
    const unsigned pos = atomicAdd(&curs[q], 1u);
    srk[pos] = rpk;
    __syncthreads();

    // P4: ballot cumulative-rank masks
    const unsigned rsv = srk[p];
    #pragma unroll
    for (int t = 0; t < 4; ++t) {
        const unsigned rt = (rsv >> (8 * t)) & 0xFFu;
        #pragma unroll
        for (int w = 0; w < 4; ++w) {
            const unsigned long long m = __ballot(rt <= (unsigned)w);
            if ((p & 63) == 0) cm[wv][t * 4 + w] = m;
        }
    }
    __syncthreads();
    if (p < 16) {
        unsigned c = 0;
        #pragma unroll
        for (int w2 = 0; w2 < 6; ++w2) {
            cumtab[w2][p] = c;
            c += (unsigned)__popcll(cm[w2][p]);
        }
        cumtab[6][p] = c;                       // grand totals
    }
    __syncthreads();

    // P5: contribution
    const float thr = d + 1.0f;
    const int jidx = (q + S > NBIN) ? NBIN : (q + S);
    const int kidx = (q - S + 1 < 0) ? 0 : (q - S + 1);
    const unsigned P = offs[jidx];     // j-role partners: pos <  P
    const unsigned L = offs[kidx];     // k-role partners: pos >= L
    const int Pwv = (int)(P >> 6), Lwv = (int)(L >> 6);
    const unsigned long long Pmask = (1ull << (P & 63)) - 1ull;
    const unsigned long long Lmask = (1ull << (L & 63)) - 1ull;

    const int4 ri4 = *reinterpret_cast<const int4*>(rank + bi * 4);
    const unsigned rip = (unsigned)ri4.x | ((unsigned)ri4.y << 8) |
                         ((unsigned)ri4.z << 16) | ((unsigned)ri4.w << 24);

    float jacc = 0.f, kacc = 0.f;
    #pragma unroll
    for (int t = 0; t < 4; ++t) {
        const int ri = (int)((rip >> (8 * t)) & 0xFFu);
        const int ro = (int)((rpk >> (8 * t)) & 0xFFu);
        const float wt = wfl[t];
        if (ro > 0 && ro < ri) {                       // j-role
            const int w = t * 4 + (ro - 1);
            const unsigned N = cumtab[Pwv][w] +
                               (unsigned)__popcll(cm[Pwv][w] & Pmask);
            jacc += wt * (float)N;
        }
        if (ro + 1 < ri) {                             // k-role
            const int wh = t * 4 + (ri - 1);
            const int wl = t * 4 + ro;
            const unsigned cLh = cumtab[Lwv][wh] +
                                 (unsigned)__popcll(cm[Lwv][wh] & Lmask);
            const unsigned cLl = cumtab[Lwv][wl] +
                                 (unsigned)__popcll(cm[Lwv][wl] & Lmask);
            const unsigned C = (cumtab[6][wh] - cLh) - (cumtab[6][wl] - cLl);
            kacc += wt * (float)C;
        }
    }
    float contrib = jacc * thr - kacc * d;

    // block reduction
    #pragma unroll
    for (int off = 32; off > 0; off >>= 1)
        contrib += __shfl_down(contrib, off);
    if ((p & 63) == 0) red[wv] = contrib;
    __syncthreads();
    if (p == 0) {
        float s = 0.f;
        #pragma unroll
        for (int w = 0; w < 6; ++w) s += red[w];
        __hip_atomic_store(&partial[bi], s, __ATOMIC_RELEASE,
                           __HIP_MEMORY_SCOPE_AGENT);
        const unsigned t = __hip_atomic_fetch_add(tick, 1u, __ATOMIC_ACQ_REL,
                                                  __HIP_MEMORY_SCOPE_AGENT);
        lastflag = (t == NB - 1) ? 1 : 0;
    }
    __syncthreads();

    // last block folds the 384 partials -> out[0]
    if (lastflag) {
        __threadfence();
        float v = __hip_atomic_load(&partial[p], __ATOMIC_RELAXED,
                                    __HIP_MEMORY_SCOPE_AGENT);
        #pragma unroll
        for (int off = 32; off > 0; off >>= 1)
            v += __shfl_down(v, off);
        if ((p & 63) == 0) red[wv] = v;
        __syncthreads();
        if (p == 0) {
            float s = 0.f;
            #pragma unroll
            for (int w = 0; w < 6; ++w) s += red[w];
            out[0] = s;
        }
    }
}

extern "C" void kernel_launch(void* const* d_in, const int* in_sizes, int n_in,
                              void* d_out, int out_size, void* d_ws, size_t ws_size,
                              hipStream_t stream)
{
    (void)in_sizes; (void)n_in; (void)out_size; (void)ws_size;
    const float* emb  = (const float*)d_in[0];
    const float* tw   = (const float*)d_in[1];
    const int*   rank = (const int*)d_in[2];
    float* ws  = (float*)d_ws;
    float* out = (float*)d_out;

    hipMemsetAsync(ws + TICK_OFF, 0, sizeof(unsigned), stream);
    gram_kernel<<<144, 256, 0, stream>>>(emb, tw, rank, ws);
    loss_kernel<<<NB, NB, 0, stream>>>(ws + G_OFF, rank, ws + WF_OFF,
                                       ws + PART_OFF,
                                       reinterpret_cast<unsigned*>(ws + TICK_OFF),
                                       out);
}

// Round 12
// 28.909 us; speedup vs baseline: 1.1372x; 1.1372x over previous
//
#include <hip/hip_runtime.h>

#define NB   384
#define ND   256
#define EPSF 1e-6f
#define NBIN 512
#define REPS 4

// ws layout (floats):
#define WF_OFF   0                        // wf[4] = tw_t / count_t
#define PART_OFF 16                       // partial[384]
#define ETP_OFF  1024                     // uint2[64][384]: bf16-packed emb^T

__device__ __forceinline__ unsigned bf16rne(float f) {
    const unsigned b = __float_as_uint(f);
    return (b + 0x7FFFu + ((b >> 16) & 1u)) >> 16;   // round-nearest-even
}

// ---------------------------------------------------------------------------
// K1: transpose emb -> ETP[g][j] = bf16x4 of dims {4g..4g+3} of e_j.
// 32x32 LDS tile per block; block 0 also computes wf[t] = tw_t / count_t.
// ---------------------------------------------------------------------------
__global__ __launch_bounds__(256) void prep_kernel(
    const float* __restrict__ emb,
    const float* __restrict__ tw,
    const int*   __restrict__ rank,
    float* __restrict__ ws)
{
    __shared__ float    t[32][33];
    __shared__ unsigned hist[20];

    const int tid = threadIdx.x;
    const int dt  = blockIdx.x & 7;      // 8 d-tiles of 32
    const int jt  = blockIdx.x >> 3;     // 12 j-tiles of 32
    const int c   = tid & 31;
    const int r8  = tid >> 5;

    #pragma unroll
    for (int p = 0; p < 4; ++p) {
        const int j = jt * 32 + r8 + p * 8;
        const int d = dt * 32 + c;
        t[r8 + p * 8][c] = emb[(size_t)j * ND + d];    // coalesced
    }
    __syncthreads();

    // pack 4 consecutive dims of one j into uint2 (bf16 x4)
    const int jloc = tid & 31;
    const int gl   = tid >> 5;           // 0..7 (d-group within tile)
    const float v0 = t[jloc][gl * 4 + 0];
    const float v1 = t[jloc][gl * 4 + 1];
    const float v2 = t[jloc][gl * 4 + 2];
    const float v3 = t[jloc][gl * 4 + 3];
    uint2 o;
    o.x = bf16rne(v0) | (bf16rne(v1) << 16);
    o.y = bf16rne(v2) | (bf16rne(v3) << 16);
    uint2* etp = reinterpret_cast<uint2*>(ws + ETP_OFF);
    etp[(size_t)(dt * 8 + gl) * NB + jt * 32 + jloc] = o;   // coalesced 8B

    if (blockIdx.x == 0) {
        if (tid < 20) hist[tid] = 0u;
        __syncthreads();
        for (int e = tid; e < NB * 4; e += 256)
            atomicAdd(&hist[(e & 3) * 5 + rank[e]], 1u);
        __syncthreads();
        if (tid < 4) {
            double cnt = 0.0;
            unsigned below = 0;
            #pragma unroll
            for (int v = 0; v < 5; ++v) {
                unsigned hv = hist[tid * 5 + v];
                unsigned above = (unsigned)NB - below - hv;
                cnt += (double)hv * (double)below * (double)above;
                below += hv;
            }
            ws[WF_OFF + tid] = (cnt > 0.0) ? (float)((double)tw[tid] / cnt) : 0.f;
        }
    }
}

// ---------------------------------------------------------------------------
// K2: ATTRIBUTION BUILD of round-10 loss kernel.
//  - P3a..P5 (the count core) replicated REPS times, bit-identical results,
//    LICM defeated via asm-opaque q; hist re-zeroed per rep.
//  - cm/cumtab rows padded (17) to kill the P5 same-bank degeneracy
//    (old stride 128B/64B put all lanes on one bank pair).
// ---------------------------------------------------------------------------
__global__ __launch_bounds__(512) void loss_kernel(
    const float* __restrict__ emb,
    const uint2* __restrict__ etp,
    const int*   __restrict__ rank,
    const float* __restrict__ wf,
    float* __restrict__ partial)
{
    __shared__ unsigned hist[NBIN];
    __shared__ unsigned offs[NBIN + 1];
    __shared__ unsigned curs[NBIN];
    __shared__ unsigned srk[512];
    __shared__ unsigned long long cm[8][17];   // padded rows: bank-spread
    __shared__ unsigned cumtab[9][17];         // padded rows: bank-spread
    __shared__ unsigned wtot[8];
    __shared__ float    mmx[16];
    __shared__ float    sprm[2];
    __shared__ float    wfl[4];
    __shared__ float    red[8];

    const int p  = threadIdx.x;
    const int bi = blockIdx.x;
    const int wv = p >> 6;

    if (p < 4) wfl[p] = wf[p];
    if (p >= NB) srk[p] = 0xFFFFFFFFu;   // pads: rank bytes 0xFF (never counted)
    __syncthreads();

    // P1: distance (bf16 ej, f32 ei via scalar path)
    float d = 0.f;
    if (p < NB) {
        const float* ei = emb + (size_t)bi * ND;      // uniform -> s_load
        float acc = 0.f;
        for (int g0 = 0; g0 < 64; g0 += 8) {          // 8 batches of 8 loads
            uint2 l[8];
            #pragma unroll
            for (int u = 0; u < 8; ++u)
                l[u] = etp[(size_t)(g0 + u) * NB + p];
            #pragma unroll
            for (int u = 0; u < 8; ++u) {
                const int dd = (g0 + u) * 4;
                const float j0 = __uint_as_float(l[u].x << 16);
                const float j1 = __uint_as_float(l[u].x & 0xFFFF0000u);
                const float j2 = __uint_as_float(l[u].y << 16);
                const float j3 = __uint_as_float(l[u].y & 0xFFFF0000u);
                const float t0 = ei[dd + 0] - j0;
                const float t1 = ei[dd + 1] - j1;
                const float t2 = ei[dd + 2] - j2;
                const float t3 = ei[dd + 3] - j3;
                acc = fmaf(t0, t0, acc);
                acc = fmaf(t1, t1, acc);
                acc = fmaf(t2, t2, acc);
                acc = fmaf(t3, t3, acc);
            }
        }
        d = sqrtf(acc);
    }

    // P2: min/max -> integer scale (outside the rep loop; cheap, no LDS state)
    float dl = (p < NB) ? d : 3.0e38f;
    float dh = (p < NB) ? d : -3.0e38f;
    #pragma unroll
    for (int off = 32; off > 0; off >>= 1) {
        dl = fminf(dl, __shfl_xor(dl, off, 64));
        dh = fmaxf(dh, __shfl_xor(dh, off, 64));
    }
    if ((p & 63) == 0) { mmx[wv] = dl; mmx[8 + wv] = dh; }
    __syncthreads();
    if (p == 0) {
        float mn = mmx[0], mx = mmx[8];
        #pragma unroll
        for (int w = 1; w < 8; ++w) {
            mn = fminf(mn, mmx[w]);
            mx = fmaxf(mx, mmx[8 + w]);
        }
        int S = (int)(511.0f / (mx - mn + 1.0f));
        if (S < 1) S = 1;
        sprm[0] = mn;
        sprm[1] = (float)S;
    }
    __syncthreads();
    const float dmin   = sprm[0];
    const float scaleF = sprm[1];
    const int   S      = (int)scaleF;

    int q0 = 0;
    unsigned rpk = 0xFFFFFFFFu;
    if (p < NB) {
        q0 = (int)((d - dmin) * scaleF);
        if (q0 > NBIN - 1) q0 = NBIN - 1;
        const int4 r4 = *reinterpret_cast<const int4*>(rank + p * 4);
        rpk = (unsigned)r4.x | ((unsigned)r4.y << 8) |
              ((unsigned)r4.z << 16) | ((unsigned)r4.w << 24);
    }
    const int4 ri4 = *reinterpret_cast<const int4*>(rank + bi * 4);
    const unsigned rip = (unsigned)ri4.x | ((unsigned)ri4.y << 8) |
                         ((unsigned)ri4.z << 16) | ((unsigned)ri4.w << 24);

    // ======================= replicated count core =======================
    float contrib = 0.f;
    int q = q0;
    for (int rep = 0; rep < REPS; ++rep) {
        asm volatile("" : "+v"(q));          // opaque: defeat LICM across reps

        hist[p] = 0u;
        __syncthreads();

        // P3a: histogram
        if (p < NB) atomicAdd(&hist[q], 1u);
        __syncthreads();

        // P3b: exclusive prefix over 512 bins
        const unsigned h = hist[p];
        unsigned inc = h;
        #pragma unroll
        for (int s = 1; s < 64; s <<= 1) {
            const unsigned o = __shfl_up(inc, s, 64);
            if ((p & 63) >= s) inc += o;
        }
        if ((p & 63) == 63) wtot[wv] = inc;
        __syncthreads();
        unsigned woff = 0;
        for (int w = 0; w < wv; ++w) woff += wtot[w];
        const unsigned excl = woff + inc - h;
        offs[p] = excl;
        curs[p] = excl;
        if (p == NBIN - 1) offs[NBIN] = excl + h;   // == NB
        __syncthreads();

        // P3c: counting scatter of rank packs into d-grouped order
        if (p < NB) {
            const unsigned pos = atomicAdd(&curs[q], 1u);
            srk[pos] = rpk;
        }
        __syncthreads();

        // P4: ballot cumulative-rank masks over scattered order
        const unsigned rsv = srk[p];
        #pragma unroll
        for (int t = 0; t < 4; ++t) {
            const unsigned rt = (rsv >> (8 * t)) & 0xFFu;
            #pragma unroll
            for (int w = 0; w < 4; ++w) {
                const unsigned long long m = __ballot(rt <= (unsigned)w);
                if ((p & 63) == 0) cm[wv][t * 4 + w] = m;
            }
        }
        __syncthreads();
        if (p < 16) {
            unsigned c = 0;
            #pragma unroll
            for (int w2 = 0; w2 < 8; ++w2) {
                cumtab[w2][p] = c;
                c += (unsigned)__popcll(cm[w2][p]);
            }
            cumtab[8][p] = c;
        }
        __syncthreads();

        // P5: per-element contribution
        float cb = 0.f;
        if (p < NB) {
            const float thr = d + 1.0f;
            const int jidx = (q + S > NBIN) ? NBIN : (q + S);
            const int kidx = (q - S + 1 < 0) ? 0 : (q - S + 1);
            const unsigned P = offs[jidx];     // j-role partners: pos <  P
            const unsigned L = offs[kidx];     // k-role partners: pos >= L
            const int Pwv = (int)(P >> 6), Lwv = (int)(L >> 6);
            const unsigned long long Pmask = (1ull << (P & 63)) - 1ull;
            const unsigned long long Lmask = (1ull << (L & 63)) - 1ull;

            float jacc = 0.f, kacc = 0.f;
            #pragma unroll
            for (int t = 0; t < 4; ++t) {
                const int ri = (int)((rip >> (8 * t)) & 0xFFu);
                const int ro = (int)((rpk >> (8 * t)) & 0xFFu);
                const float wt = wfl[t];
                if (ro > 0 && ro < ri) {                       // j-role
                    const int w = t * 4 + (ro - 1);
                    const unsigned N = cumtab[Pwv][w] +
                                       (unsigned)__popcll(cm[Pwv][w] & Pmask);
                    jacc += wt * (float)N;
                }
                if (ro + 1 < ri) {                             // k-role
                    const int wh = t * 4 + (ri - 1);
                    const int wl = t * 4 + ro;
                    const unsigned cLh = cumtab[Lwv][wh] +
                                         (unsigned)__popcll(cm[Lwv][wh] & Lmask);
                    const unsigned cLl = cumtab[Lwv][wl] +
                                         (unsigned)__popcll(cm[Lwv][wl] & Lmask);
                    const unsigned C = (cumtab[8][wh] - cLh) -
                                       (cumtab[8][wl] - cLl);
                    kacc += wt * (float)C;
                }
            }
            cb = jacc * thr - kacc * d;
        }
        contrib = cb;                        // identical every rep
        __syncthreads();                     // protect hist re-zero (WAR)
    }
    // =====================================================================

    #pragma unroll
    for (int off = 32; off > 0; off >>= 1)
        contrib += __shfl_down(contrib, off);
    if ((p & 63) == 0) red[wv] = contrib;
    __syncthreads();
    if (p == 0) {
        float s = 0.f;
        #pragma unroll
        for (int w = 0; w < 8; ++w) s += red[w];
        partial[bi] = s;
    }
}

// ---------------------------------------------------------------------------
// K3: reduce 384 partials -> out[0]
// ---------------------------------------------------------------------------
__global__ __launch_bounds__(256) void reduce_kernel(
    const float* __restrict__ partial, float* __restrict__ out)
{
    __shared__ float r[4];
    const int tid = threadIdx.x;
    float t = 0.f;
    for (int p = tid; p < NB; p += 256) t += partial[p];
    #pragma unroll
    for (int off = 32; off > 0; off >>= 1)
        t += __shfl_down(t, off);
    if ((tid & 63) == 0) r[tid >> 6] = t;
    __syncthreads();
    if (tid == 0) out[0] = r[0] + r[1] + r[2] + r[3];
}

extern "C" void kernel_launch(void* const* d_in, const int* in_sizes, int n_in,
                              void* d_out, int out_size, void* d_ws, size_t ws_size,
                              hipStream_t stream)
{
    (void)in_sizes; (void)n_in; (void)out_size; (void)ws_size;
    const float* emb  = (const float*)d_in[0];
    const float* tw   = (const float*)d_in[1];
    const int*   rank = (const int*)d_in[2];
    float* ws  = (float*)d_ws;
    float* out = (float*)d_out;

    prep_kernel<<<96, 256, 0, stream>>>(emb, tw, rank, ws);
    loss_kernel<<<NB, 512, 0, stream>>>(
        emb, reinterpret_cast<const uint2*>(ws + ETP_OFF), rank,
        ws + WF_OFF, ws + PART_OFF);
    reduce_kernel<<<1, 256, 0, stream>>>(ws + PART_OFF, out);
}

// Round 13
// 28.511 us; speedup vs baseline: 1.1531x; 1.0140x over previous
//
#include <hip/hip_runtime.h>

#define NB   384
#define ND   256
#define EPSF 1e-6f
#define NBIN 384

// ws layout (floats):
#define WF_OFF   0                        // wf[4] = tw_t / count_t
#define TICK_OFF 8                        // unsigned done-ticket (prep zeroes)
#define PART_OFF 16                       // partial[384]
#define ETP_OFF  1024                     // uint2[64][384]: bf16-packed emb^T

__device__ __forceinline__ unsigned bf16rne(float f) {
    const unsigned b = __float_as_uint(f);
    return (b + 0x7FFFu + ((b >> 16) & 1u)) >> 16;   // round-nearest-even
}

// ---------------------------------------------------------------------------
// K1: transpose emb -> ETP[g][j] = bf16x4 of dims {4g..4g+3} of (e_j - eps).
// 32x32 LDS tile per block; block 0 also computes wf[t] = tw_t / count_t and
// zeroes the done-ticket (stream order makes it visible to K2).
// ---------------------------------------------------------------------------
__global__ __launch_bounds__(256) void prep_kernel(
    const float* __restrict__ emb,
    const float* __restrict__ tw,
    const int*   __restrict__ rank,
    float* __restrict__ ws)
{
    __shared__ float    t[32][33];
    __shared__ unsigned hist[20];

    const int tid = threadIdx.x;
    const int dt  = blockIdx.x & 7;      // 8 d-tiles of 32
    const int jt  = blockIdx.x >> 3;     // 12 j-tiles of 32
    const int c   = tid & 31;
    const int r8  = tid >> 5;

    #pragma unroll
    for (int p = 0; p < 4; ++p) {
        const int j = jt * 32 + r8 + p * 8;
        const int d = dt * 32 + c;
        t[r8 + p * 8][c] = emb[(size_t)j * ND + d];    // coalesced
    }
    __syncthreads();

    // pack 4 consecutive dims of one j into uint2 (bf16 x4), eps folded
    const int jloc = tid & 31;
    const int gl   = tid >> 5;           // 0..7 (d-group within tile)
    const float v0 = t[jloc][gl * 4 + 0] - EPSF;
    const float v1 = t[jloc][gl * 4 + 1] - EPSF;
    const float v2 = t[jloc][gl * 4 + 2] - EPSF;
    const float v3 = t[jloc][gl * 4 + 3] - EPSF;
    uint2 o;
    o.x = bf16rne(v0) | (bf16rne(v1) << 16);
    o.y = bf16rne(v2) | (bf16rne(v3) << 16);
    uint2* etp = reinterpret_cast<uint2*>(ws + ETP_OFF);
    etp[(size_t)(dt * 8 + gl) * NB + jt * 32 + jloc] = o;   // coalesced 8B

    if (blockIdx.x == 0) {
        if (tid == 0)
            *reinterpret_cast<unsigned*>(ws + TICK_OFF) = 0u;  // ticket reset
        if (tid < 20) hist[tid] = 0u;
        __syncthreads();
        for (int e = tid; e < NB * 4; e += 256)
            atomicAdd(&hist[(e & 3) * 5 + rank[e]], 1u);
        __syncthreads();
        if (tid < 4) {
            double cnt = 0.0;
            unsigned below = 0;
            #pragma unroll
            for (int v = 0; v < 5; ++v) {
                unsigned hv = hist[tid * 5 + v];
                unsigned above = (unsigned)NB - below - hv;
                cnt += (double)hv * (double)below * (double)above;
                below += hv;
            }
            ws[WF_OFF + tid] = (cnt > 0.0) ? (float)((double)tw[tid] / cnt) : 0.f;
        }
    }
}

// ---------------------------------------------------------------------------
// K2: one block per row i, 384 threads (1:1 with elements, no pad lanes).
//  P1: d_p from bf16 ETP (coalesced 8B lane loads); e_i wave-uniform -> s_load
//  P2: min (excl self) / max -> integer bins-per-unit S; bin(d+1)==bin(d)+S
//  P3: 384-bin histogram -> shfl prefix scan -> counting scatter of rank packs
//  P4: ballot cumulative-rank masks over d-grouped order (bank-padded tables)
//  P5: j-role/k-role counting at bin-boundary cuts (identical pair sets)
//  Tail: partial release-store; acq-rel ticket; LAST block folds -> out[0].
// ---------------------------------------------------------------------------
__global__ __launch_bounds__(NB) void loss_kernel(
    const float* __restrict__ emb,
    const uint2* __restrict__ etp,
    const int*   __restrict__ rank,
    const float* __restrict__ wf,
    float*       __restrict__ partial,
    unsigned*    __restrict__ tick,
    float*       __restrict__ out)
{
    __shared__ unsigned hist[NBIN];
    __shared__ unsigned offs[NBIN + 1];
    __shared__ unsigned curs[NBIN];
    __shared__ unsigned srk[NB];
    __shared__ unsigned long long cm[7][17];   // row 6 zero; padded rows
    __shared__ unsigned cumtab[7][17];         // row 6 totals; padded rows
    __shared__ unsigned wtot[6];
    __shared__ float    mmx[12];
    __shared__ float    sprm[2];
    __shared__ float    wfl[4];
    __shared__ float    red[6];
    __shared__ int      lastflag;

    const int p  = threadIdx.x;        // 0..383
    const int bi = blockIdx.x;
    const int wv = p >> 6;             // 0..5

    if (p < 4)  wfl[p] = wf[p];
    if (p < 17) cm[6][p] = 0ull;
    hist[p] = 0u;

    // P1: distance (bf16 ej from ETP, f32 ei via scalar path)
    const float* ei = emb + (size_t)bi * ND;      // uniform -> s_load
    float acc = 0.f;
    for (int g0 = 0; g0 < 64; g0 += 8) {          // 8 batches of 8 loads
        uint2 l[8];
        #pragma unroll
        for (int u = 0; u < 8; ++u)
            l[u] = etp[(size_t)(g0 + u) * NB + p];
        #pragma unroll
        for (int u = 0; u < 8; ++u) {
            const int dd = (g0 + u) * 4;
            const float j0 = __uint_as_float(l[u].x << 16);
            const float j1 = __uint_as_float(l[u].x & 0xFFFF0000u);
            const float j2 = __uint_as_float(l[u].y << 16);
            const float j3 = __uint_as_float(l[u].y & 0xFFFF0000u);
            const float t0 = ei[dd + 0] - j0;
            const float t1 = ei[dd + 1] - j1;
            const float t2 = ei[dd + 2] - j2;
            const float t3 = ei[dd + 3] - j3;
            acc = fmaf(t0, t0, acc);
            acc = fmaf(t1, t1, acc);
            acc = fmaf(t2, t2, acc);
            acc = fmaf(t3, t3, acc);
        }
    }
    const float d = sqrtf(acc);

    // P2: min (excluding self) / max -> integer scale
    float dl = (p == bi) ? 3.0e38f : d;
    float dh = d;
    #pragma unroll
    for (int off = 32; off > 0; off >>= 1) {
        dl = fminf(dl, __shfl_xor(dl, off, 64));
        dh = fmaxf(dh, __shfl_xor(dh, off, 64));
    }
    if ((p & 63) == 0) { mmx[wv] = dl; mmx[6 + wv] = dh; }
    __syncthreads();
    if (p == 0) {
        float mn = mmx[0], mx = mmx[6];
        #pragma unroll
        for (int w = 1; w < 6; ++w) {
            mn = fminf(mn, mmx[w]);
            mx = fmaxf(mx, mmx[6 + w]);
        }
        int S = (int)(383.0f / (mx - mn + 1.0f));
        if (S < 1) S = 1;
        sprm[0] = mn;
        sprm[1] = (float)S;
    }
    __syncthreads();
    const float dmin   = sprm[0];
    const float scaleF = sprm[1];
    const int   S      = (int)scaleF;

    // P3a: histogram (self lands in bin 0; rank logic excludes it exactly)
    int q = (int)((d - dmin) * scaleF);
    if (q < 0) q = 0;
    if (q > NBIN - 1) q = NBIN - 1;
    atomicAdd(&hist[q], 1u);
    const int4 r4 = *reinterpret_cast<const int4*>(rank + p * 4);
    const unsigned rpk = (unsigned)r4.x | ((unsigned)r4.y << 8) |
                         ((unsigned)r4.z << 16) | ((unsigned)r4.w << 24);
    __syncthreads();

    // P3b: exclusive prefix over 384 bins
    const unsigned h = hist[p];
    unsigned inc = h;
    #pragma unroll
    for (int s = 1; s < 64; s <<= 1) {
        const unsigned o = __shfl_up(inc, s, 64);
        if ((p & 63) >= s) inc += o;
    }
    if ((p & 63) == 63) wtot[wv] = inc;
    __syncthreads();
    unsigned woff = 0;
    for (int w = 0; w < wv; ++w) woff += wtot[w];
    const unsigned excl = woff + inc - h;
    offs[p] = excl;
    curs[p] = excl;
    if (p == NBIN - 1) offs[NBIN] = excl + h;   // == NB
    __syncthreads();

    // P3c: counting scatter into d-grouped order
    const unsigned pos = atomicAdd(&curs[q], 1u);
    srk[pos] = rpk;
    __syncthreads();

    // P4: ballot cumulative-rank masks
    const unsigned rsv = srk[p];
    #pragma unroll
    for (int t = 0; t < 4; ++t) {
        const unsigned rt = (rsv >> (8 * t)) & 0xFFu;
        #pragma unroll
        for (int w = 0; w < 4; ++w) {
            const unsigned long long m = __ballot(rt <= (unsigned)w);
            if ((p & 63) == 0) cm[wv][t * 4 + w] = m;
        }
    }
    __syncthreads();
    if (p < 16) {
        unsigned c = 0;
        #pragma unroll
        for (int w2 = 0; w2 < 6; ++w2) {
            cumtab[w2][p] = c;
            c += (unsigned)__popcll(cm[w2][p]);
        }
        cumtab[6][p] = c;                       // grand totals
    }
    __syncthreads();

    // P5: contribution
    const float thr = d + 1.0f;
    const int jidx = (q + S > NBIN) ? NBIN : (q + S);
    const int kidx = (q - S + 1 < 0) ? 0 : (q - S + 1);
    const unsigned P = offs[jidx];     // j-role partners: pos <  P
    const unsigned L = offs[kidx];     // k-role partners: pos >= L
    const int Pwv = (int)(P >> 6), Lwv = (int)(L >> 6);
    const unsigned long long Pmask = (1ull << (P & 63)) - 1ull;
    const unsigned long long Lmask = (1ull << (L & 63)) - 1ull;

    const int4 ri4 = *reinterpret_cast<const int4*>(rank + bi * 4);
    const unsigned rip = (unsigned)ri4.x | ((unsigned)ri4.y << 8) |
                         ((unsigned)ri4.z << 16) | ((unsigned)ri4.w << 24);

    float jacc = 0.f, kacc = 0.f;
    #pragma unroll
    for (int t = 0; t < 4; ++t) {
        const int ri = (int)((rip >> (8 * t)) & 0xFFu);
        const int ro = (int)((rpk >> (8 * t)) & 0xFFu);
        const float wt = wfl[t];
        if (ro > 0 && ro < ri) {                       // j-role
            const int w = t * 4 + (ro - 1);
            const unsigned N = cumtab[Pwv][w] +
                               (unsigned)__popcll(cm[Pwv][w] & Pmask);
            jacc += wt * (float)N;
        }
        if (ro + 1 < ri) {                             // k-role
            const int wh = t * 4 + (ri - 1);
            const int wl = t * 4 + ro;
            const unsigned cLh = cumtab[Lwv][wh] +
                                 (unsigned)__popcll(cm[Lwv][wh] & Lmask);
            const unsigned cLl = cumtab[Lwv][wl] +
                                 (unsigned)__popcll(cm[Lwv][wl] & Lmask);
            const unsigned C = (cumtab[6][wh] - cLh) - (cumtab[6][wl] - cLl);
            kacc += wt * (float)C;
        }
    }
    float contrib = jacc * thr - kacc * d;

    // block reduction
    #pragma unroll
    for (int off = 32; off > 0; off >>= 1)
        contrib += __shfl_down(contrib, off);
    if ((p & 63) == 0) red[wv] = contrib;
    __syncthreads();
    if (p == 0) {
        float s = 0.f;
        #pragma unroll
        for (int w = 0; w < 6; ++w) s += red[w];
        __hip_atomic_store(&partial[bi], s, __ATOMIC_RELEASE,
                           __HIP_MEMORY_SCOPE_AGENT);
        const unsigned t = __hip_atomic_fetch_add(tick, 1u, __ATOMIC_ACQ_REL,
                                                  __HIP_MEMORY_SCOPE_AGENT);
        lastflag = (t == NB - 1) ? 1 : 0;
    }
    __syncthreads();

    // last block folds the 384 partials -> out[0]
    if (lastflag) {
        __threadfence();
        float v = __hip_atomic_load(&partial[p], __ATOMIC_RELAXED,
                                    __HIP_MEMORY_SCOPE_AGENT);
        #pragma unroll
        for (int off = 32; off > 0; off >>= 1)
            v += __shfl_down(v, off);
        if ((p & 63) == 0) red[wv] = v;
        __syncthreads();
        if (p == 0) {
            float s = 0.f;
            #pragma unroll
            for (int w = 0; w < 6; ++w) s += red[w];
            out[0] = s;
        }
    }
}

extern "C" void kernel_launch(void* const* d_in, const int* in_sizes, int n_in,
                              void* d_out, int out_size, void* d_ws, size_t ws_size,
                              hipStream_t stream)
{
    (void)in_sizes; (void)n_in; (void)out_size; (void)ws_size;
    const float* emb  = (const float*)d_in[0];
    const float* tw   = (const float*)d_in[1];
    const int*   rank = (const int*)d_in[2];
    float* ws  = (float*)d_ws;
    float* out = (float*)d_out;

    prep_kernel<<<96, 256, 0, stream>>>(emb, tw, rank, ws);
    loss_kernel<<<NB, NB, 0, stream>>>(
        emb, reinterpret_cast<const uint2*>(ws + ETP_OFF), rank,
        ws + WF_OFF, ws + PART_OFF,
        reinterpret_cast<unsigned*>(ws + TICK_OFF), out);
}

// Round 14
// 25.165 us; speedup vs baseline: 1.3064x; 1.1330x over previous
//
#include <hip/hip_runtime.h>

#define NB   384
#define ND   256
#define EPSF 1e-6f
#define NBIN 384
#define NPART (NB * 2)

// ws layout (floats):
#define WF_OFF   0                        // wf[4] = tw_t / count_t
#define PART_OFF 16                       // partial[768]
#define ETP_OFF  1024                     // uint2[64][384]: bf16-packed emb^T

__device__ __forceinline__ unsigned bf16rne(float f) {
    const unsigned b = __float_as_uint(f);
    return (b + 0x7FFFu + ((b >> 16) & 1u)) >> 16;   // round-nearest-even
}

// ---------------------------------------------------------------------------
// K1: transpose emb -> ETP[g][j] = bf16x4 of dims {4g..4g+3} of (e_j - eps).
// 32x32 LDS tile per block; block 0 also computes wf[t] = tw_t / count_t.
// ---------------------------------------------------------------------------
__global__ __launch_bounds__(256) void prep_kernel(
    const float* __restrict__ emb,
    const float* __restrict__ tw,
    const int*   __restrict__ rank,
    float* __restrict__ ws)
{
    __shared__ float    t[32][33];
    __shared__ unsigned hist[20];

    const int tid = threadIdx.x;
    const int dt  = blockIdx.x & 7;      // 8 d-tiles of 32
    const int jt  = blockIdx.x >> 3;     // 12 j-tiles of 32
    const int c   = tid & 31;
    const int r8  = tid >> 5;

    #pragma unroll
    for (int p = 0; p < 4; ++p) {
        const int j = jt * 32 + r8 + p * 8;
        const int d = dt * 32 + c;
        t[r8 + p * 8][c] = emb[(size_t)j * ND + d];    // coalesced
    }
    __syncthreads();

    // pack 4 consecutive dims of one j into uint2 (bf16 x4), eps folded
    const int jloc = tid & 31;
    const int gl   = tid >> 5;           // 0..7 (d-group within tile)
    const float v0 = t[jloc][gl * 4 + 0] - EPSF;
    const float v1 = t[jloc][gl * 4 + 1] - EPSF;
    const float v2 = t[jloc][gl * 4 + 2] - EPSF;
    const float v3 = t[jloc][gl * 4 + 3] - EPSF;
    uint2 o;
    o.x = bf16rne(v0) | (bf16rne(v1) << 16);
    o.y = bf16rne(v2) | (bf16rne(v3) << 16);
    uint2* etp = reinterpret_cast<uint2*>(ws + ETP_OFF);
    etp[(size_t)(dt * 8 + gl) * NB + jt * 32 + jloc] = o;   // coalesced 8B

    if (blockIdx.x == 0) {
        if (tid < 20) hist[tid] = 0u;
        __syncthreads();
        for (int e = tid; e < NB * 4; e += 256)
            atomicAdd(&hist[(e & 3) * 5 + rank[e]], 1u);
        __syncthreads();
        if (tid < 4) {
            double cnt = 0.0;
            unsigned below = 0;
            #pragma unroll
            for (int v = 0; v < 5; ++v) {
                unsigned hv = hist[tid * 5 + v];
                unsigned above = (unsigned)NB - below - hv;
                cnt += (double)hv * (double)below * (double)above;
                below += hv;
            }
            ws[WF_OFF + tid] = (cnt > 0.0) ? (float)((double)tw[tid] / cnt) : 0.f;
        }
    }
}

// ---------------------------------------------------------------------------
// K2: TWO blocks per row i (role 0: j-side sum, role 1: k-side sum).
// 768 blocks x 384 threads = 3 blocks/CU, 18 waves/CU -- latency hiding via
// block-level TLP; P1..P4 are redundantly computed by both role-blocks
// (cheap issue work that fills the other block's stall bubbles).
//  P1: d_p from bf16 ETP (coalesced 8B); e_i wave-uniform -> scalar path
//  P2: min (excl self) / max -> integer bins-per-unit S (bin(d+1)=bin(d)+S)
//  P3: 384-bin histogram -> shfl prefix scan -> counting scatter of rank packs
//  P4: ballot cumulative-rank masks over d-grouped order (bank-padded)
//  P5: role 0: +thr_p * sum_t wf_t * #{pos<P: r^t<r^t_p}      [r^t_p < r^t_i]
//      role 1: -d_p  * sum_t wf_t * #{pos>=L: r^t_p<r^t<r^t_i}
//      (both roles use the same bin-boundary cuts -> pair sets identical)
// ---------------------------------------------------------------------------
__global__ __launch_bounds__(NB) void loss_kernel(
    const float* __restrict__ emb,
    const uint2* __restrict__ etp,
    const int*   __restrict__ rank,
    const float* __restrict__ wf,
    float*       __restrict__ partial)
{
    __shared__ unsigned hist[NBIN];
    __shared__ unsigned offs[NBIN + 1];
    __shared__ unsigned curs[NBIN];
    __shared__ unsigned srk[NB];
    __shared__ unsigned long long cm[7][17];   // row 6 zero; padded rows
    __shared__ unsigned cumtab[7][17];         // row 6 totals; padded rows
    __shared__ unsigned wtot[6];
    __shared__ float    mmx[12];
    __shared__ float    sprm[2];
    __shared__ float    wfl[4];
    __shared__ float    red[6];

    const int p    = threadIdx.x;      // 0..383
    const int bi   = blockIdx.x >> 1;  // row
    const int role = blockIdx.x & 1;   // 0: j-side, 1: k-side
    const int wv   = p >> 6;           // 0..5

    if (p < 4)  wfl[p] = wf[p];
    if (p < 17) cm[6][p] = 0ull;
    hist[p] = 0u;

    // P1: distance (bf16 ej from ETP, f32 ei via scalar path)
    const float* ei = emb + (size_t)bi * ND;      // uniform -> s_load
    float acc = 0.f;
    for (int g0 = 0; g0 < 64; g0 += 8) {          // 8 batches of 8 loads
        uint2 l[8];
        #pragma unroll
        for (int u = 0; u < 8; ++u)
            l[u] = etp[(size_t)(g0 + u) * NB + p];
        #pragma unroll
        for (int u = 0; u < 8; ++u) {
            const int dd = (g0 + u) * 4;
            const float j0 = __uint_as_float(l[u].x << 16);
            const float j1 = __uint_as_float(l[u].x & 0xFFFF0000u);
            const float j2 = __uint_as_float(l[u].y << 16);
            const float j3 = __uint_as_float(l[u].y & 0xFFFF0000u);
            const float t0 = ei[dd + 0] - j0;
            const float t1 = ei[dd + 1] - j1;
            const float t2 = ei[dd + 2] - j2;
            const float t3 = ei[dd + 3] - j3;
            acc = fmaf(t0, t0, acc);
            acc = fmaf(t1, t1, acc);
            acc = fmaf(t2, t2, acc);
            acc = fmaf(t3, t3, acc);
        }
    }
    const float d = sqrtf(acc);

    // P2: min (excluding self) / max -> integer scale
    float dl = (p == bi) ? 3.0e38f : d;
    float dh = d;
    #pragma unroll
    for (int off = 32; off > 0; off >>= 1) {
        dl = fminf(dl, __shfl_xor(dl, off, 64));
        dh = fmaxf(dh, __shfl_xor(dh, off, 64));
    }
    if ((p & 63) == 0) { mmx[wv] = dl; mmx[6 + wv] = dh; }
    __syncthreads();
    if (p == 0) {
        float mn = mmx[0], mx = mmx[6];
        #pragma unroll
        for (int w = 1; w < 6; ++w) {
            mn = fminf(mn, mmx[w]);
            mx = fmaxf(mx, mmx[6 + w]);
        }
        int S = (int)(383.0f / (mx - mn + 1.0f));
        if (S < 1) S = 1;
        sprm[0] = mn;
        sprm[1] = (float)S;
    }
    __syncthreads();
    const float dmin   = sprm[0];
    const float scaleF = sprm[1];
    const int   S      = (int)scaleF;

    // P3a: histogram (self clamps to bin 0; rank strictness excludes it)
    int q = (int)((d - dmin) * scaleF);
    if (q < 0) q = 0;
    if (q > NBIN - 1) q = NBIN - 1;
    atomicAdd(&hist[q], 1u);
    const int4 r4 = *reinterpret_cast<const int4*>(rank + p * 4);
    const unsigned rpk = (unsigned)r4.x | ((unsigned)r4.y << 8) |
                         ((unsigned)r4.z << 16) | ((unsigned)r4.w << 24);
    __syncthreads();

    // P3b: exclusive prefix over 384 bins
    const unsigned h = hist[p];
    unsigned inc = h;
    #pragma unroll
    for (int s = 1; s < 64; s <<= 1) {
        const unsigned o = __shfl_up(inc, s, 64);
        if ((p & 63) >= s) inc += o;
    }
    if ((p & 63) == 63) wtot[wv] = inc;
    __syncthreads();
    unsigned woff = 0;
    for (int w = 0; w < wv; ++w) woff += wtot[w];
    const unsigned excl = woff + inc - h;
    offs[p] = excl;
    curs[p] = excl;
    if (p == NBIN - 1) offs[NBIN] = excl + h;   // == NB
    __syncthreads();

    // P3c: counting scatter into d-grouped order
    const unsigned pos = atomicAdd(&curs[q], 1u);
    srk[pos] = rpk;
    __syncthreads();

    // P4: ballot cumulative-rank masks
    const unsigned rsv = srk[p];
    #pragma unroll
    for (int t = 0; t < 4; ++t) {
        const unsigned rt = (rsv >> (8 * t)) & 0xFFu;
        #pragma unroll
        for (int w = 0; w < 4; ++w) {
            const unsigned long long m = __ballot(rt <= (unsigned)w);
            if ((p & 63) == 0) cm[wv][t * 4 + w] = m;
        }
    }
    __syncthreads();
    if (p < 16) {
        unsigned c = 0;
        #pragma unroll
        for (int w2 = 0; w2 < 6; ++w2) {
            cumtab[w2][p] = c;
            c += (unsigned)__popcll(cm[w2][p]);
        }
        cumtab[6][p] = c;                       // grand totals
    }
    __syncthreads();

    // P5: role-split contribution
    const int4 ri4 = *reinterpret_cast<const int4*>(rank + bi * 4);
    const unsigned rip = (unsigned)ri4.x | ((unsigned)ri4.y << 8) |
                         ((unsigned)ri4.z << 16) | ((unsigned)ri4.w << 24);

    float contrib;
    if (role == 0) {                            // j-side
        const int jidx = (q + S > NBIN) ? NBIN : (q + S);
        const unsigned P = offs[jidx];          // partners: pos < P
        const int Pwv = (int)(P >> 6);
        const unsigned long long Pmask = (1ull << (P & 63)) - 1ull;
        float jacc = 0.f;
        #pragma unroll
        for (int t = 0; t < 4; ++t) {
            const int ri = (int)((rip >> (8 * t)) & 0xFFu);
            const int ro = (int)((rpk >> (8 * t)) & 0xFFu);
            if (ro > 0 && ro < ri) {
                const int w = t * 4 + (ro - 1);
                const unsigned N = cumtab[Pwv][w] +
                                   (unsigned)__popcll(cm[Pwv][w] & Pmask);
                jacc += wfl[t] * (float)N;
            }
        }
        contrib = jacc * (d + 1.0f);
    } else {                                    // k-side
        const int kidx = (q - S + 1 < 0) ? 0 : (q - S + 1);
        const unsigned L = offs[kidx];          // partners: pos >= L
        const int Lwv = (int)(L >> 6);
        const unsigned long long Lmask = (1ull << (L & 63)) - 1ull;
        float kacc = 0.f;
        #pragma unroll
        for (int t = 0; t < 4; ++t) {
            const int ri = (int)((rip >> (8 * t)) & 0xFFu);
            const int ro = (int)((rpk >> (8 * t)) & 0xFFu);
            if (ro + 1 < ri) {
                const int wh = t * 4 + (ri - 1);
                const int wl = t * 4 + ro;
                const unsigned cLh = cumtab[Lwv][wh] +
                                     (unsigned)__popcll(cm[Lwv][wh] & Lmask);
                const unsigned cLl = cumtab[Lwv][wl] +
                                     (unsigned)__popcll(cm[Lwv][wl] & Lmask);
                const unsigned C = (cumtab[6][wh] - cLh) - (cumtab[6][wl] - cLl);
                kacc += wfl[t] * (float)C;
            }
        }
        contrib = -kacc * d;
    }

    // block reduction
    #pragma unroll
    for (int off = 32; off > 0; off >>= 1)
        contrib += __shfl_down(contrib, off);
    if ((p & 63) == 0) red[wv] = contrib;
    __syncthreads();
    if (p == 0) {
        float s = 0.f;
        #pragma unroll
        for (int w = 0; w < 6; ++w) s += red[w];
        partial[blockIdx.x] = s;
    }
}

// ---------------------------------------------------------------------------
// K3: reduce 768 partials -> out[0]
// ---------------------------------------------------------------------------
__global__ __launch_bounds__(256) void reduce_kernel(
    const float* __restrict__ partial, float* __restrict__ out)
{
    __shared__ float r[4];
    const int tid = threadIdx.x;
    float t = 0.f;
    for (int p = tid; p < NPART; p += 256) t += partial[p];
    #pragma unroll
    for (int off = 32; off > 0; off >>= 1)
        t += __shfl_down(t, off);
    if ((tid & 63) == 0) r[tid >> 6] = t;
    __syncthreads();
    if (tid == 0) out[0] = r[0] + r[1] + r[2] + r[3];
}

extern "C" void kernel_launch(void* const* d_in, const int* in_sizes, int n_in,
                              void* d_out, int out_size, void* d_ws, size_t ws_size,
                              hipStream_t stream)
{
    (void)in_sizes; (void)n_in; (void)out_size; (void)ws_size;
    const float* emb  = (const float*)d_in[0];
    const float* tw   = (const float*)d_in[1];
    const int*   rank = (const int*)d_in[2];
    float* ws  = (float*)d_ws;
    float* out = (float*)d_out;

    prep_kernel<<<96, 256, 0, stream>>>(emb, tw, rank, ws);
    loss_kernel<<<NB * 2, NB, 0, stream>>>(
        emb, reinterpret_cast<const uint2*>(ws + ETP_OFF), rank,
        ws + WF_OFF, ws + PART_OFF);
    reduce_kernel<<<1, 256, 0, stream>>>(ws + PART_OFF, out);
}

// Round 15
// 22.554 us; speedup vs baseline: 1.4577x; 1.1158x over previous
//
#include <hip/hip_runtime.h>

#define NB   384
#define ND   256
#define EPSF 1e-6f
#define NBIN 384

// ws layout (floats):
#define WF_OFF   0                        // wf[4] = tw_t / count_t
#define PART_OFF 16                       // partial[384]
#define ETP_OFF  1024                     // uint2[64][384]: bf16-packed emb^T

__device__ __forceinline__ unsigned bf16rne(float f) {
    const unsigned b = __float_as_uint(f);
    return (b + 0x7FFFu + ((b >> 16) & 1u)) >> 16;   // round-nearest-even
}

// ---------------------------------------------------------------------------
// K1: transpose emb -> ETP[g][j] = bf16x4 of dims {4g..4g+3} of (e_j - eps).
// 32x32 LDS tile per block; block 0 also computes wf[t] = tw_t / count_t.
// ---------------------------------------------------------------------------
__global__ __launch_bounds__(256) void prep_kernel(
    const float* __restrict__ emb,
    const float* __restrict__ tw,
    const int*   __restrict__ rank,
    float* __restrict__ ws)
{
    __shared__ float    t[32][33];
    __shared__ unsigned hist[20];

    const int tid = threadIdx.x;
    const int dt  = blockIdx.x & 7;      // 8 d-tiles of 32
    const int jt  = blockIdx.x >> 3;     // 12 j-tiles of 32
    const int c   = tid & 31;
    const int r8  = tid >> 5;

    #pragma unroll
    for (int p = 0; p < 4; ++p) {
        const int j = jt * 32 + r8 + p * 8;
        const int d = dt * 32 + c;
        t[r8 + p * 8][c] = emb[(size_t)j * ND + d];    // coalesced
    }
    __syncthreads();

    // pack 4 consecutive dims of one j into uint2 (bf16 x4), eps folded
    const int jloc = tid & 31;
    const int gl   = tid >> 5;           // 0..7 (d-group within tile)
    const float v0 = t[jloc][gl * 4 + 0] - EPSF;
    const float v1 = t[jloc][gl * 4 + 1] - EPSF;
    const float v2 = t[jloc][gl * 4 + 2] - EPSF;
    const float v3 = t[jloc][gl * 4 + 3] - EPSF;
    uint2 o;
    o.x = bf16rne(v0) | (bf16rne(v1) << 16);
    o.y = bf16rne(v2) | (bf16rne(v3) << 16);
    uint2* etp = reinterpret_cast<uint2*>(ws + ETP_OFF);
    etp[(size_t)(dt * 8 + gl) * NB + jt * 32 + jloc] = o;   // coalesced 8B

    if (blockIdx.x == 0) {
        if (tid < 20) hist[tid] = 0u;
        __syncthreads();
        for (int e = tid; e < NB * 4; e += 256)
            atomicAdd(&hist[(e & 3) * 5 + rank[e]], 1u);
        __syncthreads();
        if (tid < 4) {
            double cnt = 0.0;
            unsigned below = 0;
            #pragma unroll
            for (int v = 0; v < 5; ++v) {
                unsigned hv = hist[tid * 5 + v];
                unsigned above = (unsigned)NB - below - hv;
                cnt += (double)hv * (double)below * (double)above;
                below += hv;
            }
            ws[WF_OFF + tid] = (cnt > 0.0) ? (float)((double)tw[tid] / cnt) : 0.f;
        }
    }
}

// ---------------------------------------------------------------------------
// K2: one block per row i, 384 threads (1:1 with elements -- no pad lanes,
// so P1 issues zero wasted work). Proven bit-exact in rounds 13/14.
//  P1: d_p from bf16 ETP (coalesced 8B); e_i wave-uniform -> scalar path
//  P2: min (excl self) / max -> integer bins-per-unit S (bin(d+1)=bin(d)+S)
//  P3: 384-bin histogram -> shfl prefix scan -> counting scatter of rank packs
//  P4: ballot cumulative-rank masks over d-grouped order (bank-padded tables)
//  P5: j-role + k-role counting at the same bin-boundary cuts (identical
//      pair sets by construction); contribution = jacc*(d+1) - kacc*d
// ---------------------------------------------------------------------------
__global__ __launch_bounds__(NB) void loss_kernel(
    const float* __restrict__ emb,
    const uint2* __restrict__ etp,
    const int*   __restrict__ rank,
    const float* __restrict__ wf,
    float*       __restrict__ partial)
{
    __shared__ unsigned hist[NBIN];
    __shared__ unsigned offs[NBIN + 1];
    __shared__ unsigned curs[NBIN];
    __shared__ unsigned srk[NB];
    __shared__ unsigned long long cm[7][17];   // row 6 zero; padded rows
    __shared__ unsigned cumtab[7][17];         // row 6 totals; padded rows
    __shared__ unsigned wtot[6];
    __shared__ float    mmx[12];
    __shared__ float    sprm[2];
    __shared__ float    wfl[4];
    __shared__ float    red[6];

    const int p  = threadIdx.x;        // 0..383
    const int bi = blockIdx.x;         // row
    const int wv = p >> 6;             // 0..5

    if (p < 4)  wfl[p] = wf[p];
    if (p < 17) cm[6][p] = 0ull;
    hist[p] = 0u;

    // P1: distance (bf16 ej from ETP, f32 ei via scalar path)
    const float* ei = emb + (size_t)bi * ND;      // uniform -> s_load
    float acc = 0.f;
    for (int g0 = 0; g0 < 64; g0 += 8) {          // 8 batches of 8 loads
        uint2 l[8];
        #pragma unroll
        for (int u = 0; u < 8; ++u)
            l[u] = etp[(size_t)(g0 + u) * NB + p];
        #pragma unroll
        for (int u = 0; u < 8; ++u) {
            const int dd = (g0 + u) * 4;
            const float j0 = __uint_as_float(l[u].x << 16);
            const float j1 = __uint_as_float(l[u].x & 0xFFFF0000u);
            const float j2 = __uint_as_float(l[u].y << 16);
            const float j3 = __uint_as_float(l[u].y & 0xFFFF0000u);
            const float t0 = ei[dd + 0] - j0;
            const float t1 = ei[dd + 1] - j1;
            const float t2 = ei[dd + 2] - j2;
            const float t3 = ei[dd + 3] - j3;
            acc = fmaf(t0, t0, acc);
            acc = fmaf(t1, t1, acc);
            acc = fmaf(t2, t2, acc);
            acc = fmaf(t3, t3, acc);
        }
    }
    const float d = sqrtf(acc);

    // P2: min (excluding self) / max -> integer scale
    float dl = (p == bi) ? 3.0e38f : d;
    float dh = d;
    #pragma unroll
    for (int off = 32; off > 0; off >>= 1) {
        dl = fminf(dl, __shfl_xor(dl, off, 64));
        dh = fmaxf(dh, __shfl_xor(dh, off, 64));
    }
    if ((p & 63) == 0) { mmx[wv] = dl; mmx[6 + wv] = dh; }
    __syncthreads();
    if (p == 0) {
        float mn = mmx[0], mx = mmx[6];
        #pragma unroll
        for (int w = 1; w < 6; ++w) {
            mn = fminf(mn, mmx[w]);
            mx = fmaxf(mx, mmx[6 + w]);
        }
        int S = (int)(383.0f / (mx - mn + 1.0f));
        if (S < 1) S = 1;
        sprm[0] = mn;
        sprm[1] = (float)S;
    }
    __syncthreads();
    const float dmin   = sprm[0];
    const float scaleF = sprm[1];
    const int   S      = (int)scaleF;

    // P3a: histogram (self clamps to bin 0; rank strictness excludes it)
    int q = (int)((d - dmin) * scaleF);
    if (q < 0) q = 0;
    if (q > NBIN - 1) q = NBIN - 1;
    atomicAdd(&hist[q], 1u);
    const int4 r4 = *reinterpret_cast<const int4*>(rank + p * 4);
    const unsigned rpk = (unsigned)r4.x | ((unsigned)r4.y << 8) |
                         ((unsigned)r4.z << 16) | ((unsigned)r4.w << 24);
    __syncthreads();

    // P3b: exclusive prefix over 384 bins
    const unsigned h = hist[p];
    unsigned inc = h;
    #pragma unroll
    for (int s = 1; s < 64; s <<= 1) {
        const unsigned o = __shfl_up(inc, s, 64);
        if ((p & 63) >= s) inc += o;
    }
    if ((p & 63) == 63) wtot[wv] = inc;
    __syncthreads();
    unsigned woff = 0;
    for (int w = 0; w < wv; ++w) woff += wtot[w];
    const unsigned excl = woff + inc - h;
    offs[p] = excl;
    curs[p] = excl;
    if (p == NBIN - 1) offs[NBIN] = excl + h;   // == NB
    __syncthreads();

    // P3c: counting scatter into d-grouped order
    const unsigned pos = atomicAdd(&curs[q], 1u);
    srk[pos] = rpk;
    __syncthreads();

    // P4: ballot cumulative-rank masks
    const unsigned rsv = srk[p];
    #pragma unroll
    for (int t = 0; t < 4; ++t) {
        const unsigned rt = (rsv >> (8 * t)) & 0xFFu;
        #pragma unroll
        for (int w = 0; w < 4; ++w) {
            const unsigned long long m = __ballot(rt <= (unsigned)w);
            if ((p & 63) == 0) cm[wv][t * 4 + w] = m;
        }
    }
    __syncthreads();
    if (p < 16) {
        unsigned c = 0;
        #pragma unroll
        for (int w2 = 0; w2 < 6; ++w2) {
            cumtab[w2][p] = c;
            c += (unsigned)__popcll(cm[w2][p]);
        }
        cumtab[6][p] = c;                       // grand totals
    }
    __syncthreads();

    // P5: contribution (both roles)
    const float thr = d + 1.0f;
    const int jidx = (q + S > NBIN) ? NBIN : (q + S);
    const int kidx = (q - S + 1 < 0) ? 0 : (q - S + 1);
    const unsigned P = offs[jidx];     // j-role partners: pos <  P
    const unsigned L = offs[kidx];     // k-role partners: pos >= L
    const int Pwv = (int)(P >> 6), Lwv = (int)(L >> 6);
    const unsigned long long Pmask = (1ull << (P & 63)) - 1ull;
    const unsigned long long Lmask = (1ull << (L & 63)) - 1ull;

    const int4 ri4 = *reinterpret_cast<const int4*>(rank + bi * 4);
    const unsigned rip = (unsigned)ri4.x | ((unsigned)ri4.y << 8) |
                         ((unsigned)ri4.z << 16) | ((unsigned)ri4.w << 24);

    float jacc = 0.f, kacc = 0.f;
    #pragma unroll
    for (int t = 0; t < 4; ++t) {
        const int ri = (int)((rip >> (8 * t)) & 0xFFu);
        const int ro = (int)((rpk >> (8 * t)) & 0xFFu);
        const float wt = wfl[t];
        if (ro > 0 && ro < ri) {                       // j-role
            const int w = t * 4 + (ro - 1);
            const unsigned N = cumtab[Pwv][w] +
                               (unsigned)__popcll(cm[Pwv][w] & Pmask);
            jacc += wt * (float)N;
        }
        if (ro + 1 < ri) {                             // k-role
            const int wh = t * 4 + (ri - 1);
            const int wl = t * 4 + ro;
            const unsigned cLh = cumtab[Lwv][wh] +
                                 (unsigned)__popcll(cm[Lwv][wh] & Lmask);
            const unsigned cLl = cumtab[Lwv][wl] +
                                 (unsigned)__popcll(cm[Lwv][wl] & Lmask);
            const unsigned C = (cumtab[6][wh] - cLh) - (cumtab[6][wl] - cLl);
            kacc += wt * (float)C;
        }
    }
    float contrib = jacc * thr - kacc * d;

    // block reduction
    #pragma unroll
    for (int off = 32; off > 0; off >>= 1)
        contrib += __shfl_down(contrib, off);
    if ((p & 63) == 0) red[wv] = contrib;
    __syncthreads();
    if (p == 0) {
        float s = 0.f;
        #pragma unroll
        for (int w = 0; w < 6; ++w) s += red[w];
        partial[bi] = s;
    }
}

// ---------------------------------------------------------------------------
// K3: reduce 384 partials -> out[0]
// ---------------------------------------------------------------------------
__global__ __launch_bounds__(256) void reduce_kernel(
    const float* __restrict__ partial, float* __restrict__ out)
{
    __shared__ float r[4];
    const int tid = threadIdx.x;
    float t = 0.f;
    for (int p = tid; p < NB; p += 256) t += partial[p];
    #pragma unroll
    for (int off = 32; off > 0; off >>= 1)
        t += __shfl_down(t, off);
    if ((tid & 63) == 0) r[tid >> 6] = t;
    __syncthreads();
    if (tid == 0) out[0] = r[0] + r[1] + r[2] + r[3];
}

extern "C" void kernel_launch(void* const* d_in, const int* in_sizes, int n_in,
                              void* d_out, int out_size, void* d_ws, size_t ws_size,
                              hipStream_t stream)
{
    (void)in_sizes; (void)n_in; (void)out_size; (void)ws_size;
    const float* emb  = (const float*)d_in[0];
    const float* tw   = (const float*)d_in[1];
    const int*   rank = (const int*)d_in[2];
    float* ws  = (float*)d_ws;
    float* out = (float*)d_out;

    prep_kernel<<<96, 256, 0, stream>>>(emb, tw, rank, ws);
    loss_kernel<<<NB, NB, 0, stream>>>(
        emb, reinterpret_cast<const uint2*>(ws + ETP_OFF), rank,
        ws + WF_OFF, ws + PART_OFF);
    reduce_kernel<<<1, 256, 0, stream>>>(ws + PART_OFF, out);
}

// Round 16
// 22.061 us; speedup vs baseline: 1.4902x; 1.0223x over previous
//
#include <hip/hip_runtime.h>

#define NB   384
#define ND   256
#define EPSF 1e-6f
#define NBIN 384
#define SENT 0xFFFFFFFFu                  // NaN bit pattern: finite sums never match

// ws layout (floats):
#define WF_OFF   0                        // wf[4] = tw_t / count_t
#define PART_OFF 16                       // partial[384] (prep sets sentinel)
#define ETP_OFF  1024                     // uint2[64][384]: bf16-packed emb^T

__device__ __forceinline__ unsigned bf16rne(float f) {
    const unsigned b = __float_as_uint(f);
    return (b + 0x7FFFu + ((b >> 16) & 1u)) >> 16;   // round-nearest-even
}

// ---------------------------------------------------------------------------
// K1: transpose emb -> ETP[g][j] = bf16x4 of dims {4g..4g+3} of (e_j - eps).
// 32x32 LDS tile per block. Block 0: wf[t] = tw_t / count_t (analytic counts).
// Block 1: reset partial[] to sentinel (stream order makes it visible to K2).
// ---------------------------------------------------------------------------
__global__ __launch_bounds__(256) void prep_kernel(
    const float* __restrict__ emb,
    const float* __restrict__ tw,
    const int*   __restrict__ rank,
    float* __restrict__ ws)
{
    __shared__ float    t[32][33];
    __shared__ unsigned hist[20];

    const int tid = threadIdx.x;
    const int dt  = blockIdx.x & 7;      // 8 d-tiles of 32
    const int jt  = blockIdx.x >> 3;     // 12 j-tiles of 32
    const int c   = tid & 31;
    const int r8  = tid >> 5;

    #pragma unroll
    for (int p = 0; p < 4; ++p) {
        const int j = jt * 32 + r8 + p * 8;
        const int d = dt * 32 + c;
        t[r8 + p * 8][c] = emb[(size_t)j * ND + d];    // coalesced
    }
    __syncthreads();

    // pack 4 consecutive dims of one j into uint2 (bf16 x4), eps folded
    const int jloc = tid & 31;
    const int gl   = tid >> 5;           // 0..7 (d-group within tile)
    const float v0 = t[jloc][gl * 4 + 0] - EPSF;
    const float v1 = t[jloc][gl * 4 + 1] - EPSF;
    const float v2 = t[jloc][gl * 4 + 2] - EPSF;
    const float v3 = t[jloc][gl * 4 + 3] - EPSF;
    uint2 o;
    o.x = bf16rne(v0) | (bf16rne(v1) << 16);
    o.y = bf16rne(v2) | (bf16rne(v3) << 16);
    uint2* etp = reinterpret_cast<uint2*>(ws + ETP_OFF);
    etp[(size_t)(dt * 8 + gl) * NB + jt * 32 + jloc] = o;   // coalesced 8B

    if (blockIdx.x == 0) {
        if (tid < 20) hist[tid] = 0u;
        __syncthreads();
        for (int e = tid; e < NB * 4; e += 256)
            atomicAdd(&hist[(e & 3) * 5 + rank[e]], 1u);
        __syncthreads();
        if (tid < 4) {
            double cnt = 0.0;
            unsigned below = 0;
            #pragma unroll
            for (int v = 0; v < 5; ++v) {
                unsigned hv = hist[tid * 5 + v];
                unsigned above = (unsigned)NB - below - hv;
                cnt += (double)hv * (double)below * (double)above;
                below += hv;
            }
            ws[WF_OFF + tid] = (cnt > 0.0) ? (float)((double)tw[tid] / cnt) : 0.f;
        }
    }
    if (blockIdx.x == 1) {
        unsigned* part = reinterpret_cast<unsigned*>(ws + PART_OFF);
        for (int p = tid; p < NB; p += 256) part[p] = SENT;
    }
}

// ---------------------------------------------------------------------------
// K2: one block per row i, 384 threads (1:1 with elements, no pad lanes).
//  P1: d_p from bf16 ETP (coalesced 8B); e_i wave-uniform -> scalar path
//  P2: min (excl self) / max -> integer bins-per-unit S (bin(d+1)=bin(d)+S)
//  P3: 384-bin histogram -> shfl prefix scan -> counting scatter of rank packs
//  P4: ballot cumulative-rank masks over d-grouped order (bank-padded tables)
//  P5: j-role + k-role counting at the same bin-boundary cuts
//  Tail: release-store own partial (independent lines, no RMW storm);
//        block NB-1 acquire-polls all 384 slots past sentinel, folds -> out.
// ---------------------------------------------------------------------------
__global__ __launch_bounds__(NB) void loss_kernel(
    const float* __restrict__ emb,
    const uint2* __restrict__ etp,
    const int*   __restrict__ rank,
    const float* __restrict__ wf,
    unsigned*    __restrict__ partial,
    float*       __restrict__ out)
{
    __shared__ unsigned hist[NBIN];
    __shared__ unsigned offs[NBIN + 1];
    __shared__ unsigned curs[NBIN];
    __shared__ unsigned srk[NB];
    __shared__ unsigned long long cm[7][17];   // row 6 zero; padded rows
    __shared__ unsigned cumtab[7][17];         // row 6 totals; padded rows
    __shared__ unsigned wtot[6];
    __shared__ float    mmx[12];
    __shared__ float    sprm[2];
    __shared__ float    wfl[4];
    __shared__ float    red[6];

    const int p  = threadIdx.x;        // 0..383
    const int bi = blockIdx.x;         // row
    const int wv = p >> 6;             // 0..5

    if (p < 4)  wfl[p] = wf[p];
    if (p < 17) cm[6][p] = 0ull;
    hist[p] = 0u;

    // P1: distance (bf16 ej from ETP, f32 ei via scalar path)
    const float* ei = emb + (size_t)bi * ND;      // uniform -> s_load
    float acc = 0.f;
    for (int g0 = 0; g0 < 64; g0 += 8) {          // 8 batches of 8 loads
        uint2 l[8];
        #pragma unroll
        for (int u = 0; u < 8; ++u)
            l[u] = etp[(size_t)(g0 + u) * NB + p];
        #pragma unroll
        for (int u = 0; u < 8; ++u) {
            const int dd = (g0 + u) * 4;
            const float j0 = __uint_as_float(l[u].x << 16);
            const float j1 = __uint_as_float(l[u].x & 0xFFFF0000u);
            const float j2 = __uint_as_float(l[u].y << 16);
            const float j3 = __uint_as_float(l[u].y & 0xFFFF0000u);
            const float t0 = ei[dd + 0] - j0;
            const float t1 = ei[dd + 1] - j1;
            const float t2 = ei[dd + 2] - j2;
            const float t3 = ei[dd + 3] - j3;
            acc = fmaf(t0, t0, acc);
            acc = fmaf(t1, t1, acc);
            acc = fmaf(t2, t2, acc);
            acc = fmaf(t3, t3, acc);
        }
    }
    const float d = sqrtf(acc);

    // P2: min (excluding self) / max -> integer scale
    float dl = (p == bi) ? 3.0e38f : d;
    float dh = d;
    #pragma unroll
    for (int off = 32; off > 0; off >>= 1) {
        dl = fminf(dl, __shfl_xor(dl, off, 64));
        dh = fmaxf(dh, __shfl_xor(dh, off, 64));
    }
    if ((p & 63) == 0) { mmx[wv] = dl; mmx[6 + wv] = dh; }
    __syncthreads();
    if (p == 0) {
        float mn = mmx[0], mx = mmx[6];
        #pragma unroll
        for (int w = 1; w < 6; ++w) {
            mn = fminf(mn, mmx[w]);
            mx = fmaxf(mx, mmx[6 + w]);
        }
        int S = (int)(383.0f / (mx - mn + 1.0f));
        if (S < 1) S = 1;
        sprm[0] = mn;
        sprm[1] = (float)S;
    }
    __syncthreads();
    const float dmin   = sprm[0];
    const float scaleF = sprm[1];
    const int   S      = (int)scaleF;

    // P3a: histogram (self clamps to bin 0; rank strictness excludes it)
    int q = (int)((d - dmin) * scaleF);
    if (q < 0) q = 0;
    if (q > NBIN - 1) q = NBIN - 1;
    atomicAdd(&hist[q], 1u);
    const int4 r4 = *reinterpret_cast<const int4*>(rank + p * 4);
    const unsigned rpk = (unsigned)r4.x | ((unsigned)r4.y << 8) |
                         ((unsigned)r4.z << 16) | ((unsigned)r4.w << 24);
    __syncthreads();

    // P3b: exclusive prefix over 384 bins
    const unsigned h = hist[p];
    unsigned inc = h;
    #pragma unroll
    for (int s = 1; s < 64; s <<= 1) {
        const unsigned o = __shfl_up(inc, s, 64);
        if ((p & 63) >= s) inc += o;
    }
    if ((p & 63) == 63) wtot[wv] = inc;
    __syncthreads();
    unsigned woff = 0;
    for (int w = 0; w < wv; ++w) woff += wtot[w];
    const unsigned excl = woff + inc - h;
    offs[p] = excl;
    curs[p] = excl;
    if (p == NBIN - 1) offs[NBIN] = excl + h;   // == NB
    __syncthreads();

    // P3c: counting scatter into d-grouped order
    const unsigned pos = atomicAdd(&curs[q], 1u);
    srk[pos] = rpk;
    __syncthreads();

    // P4: ballot cumulative-rank masks
    const unsigned rsv = srk[p];
    #pragma unroll
    for (int t = 0; t < 4; ++t) {
        const unsigned rt = (rsv >> (8 * t)) & 0xFFu;
        #pragma unroll
        for (int w = 0; w < 4; ++w) {
            const unsigned long long m = __ballot(rt <= (unsigned)w);
            if ((p & 63) == 0) cm[wv][t * 4 + w] = m;
        }
    }
    __syncthreads();
    if (p < 16) {
        unsigned c = 0;
        #pragma unroll
        for (int w2 = 0; w2 < 6; ++w2) {
            cumtab[w2][p] = c;
            c += (unsigned)__popcll(cm[w2][p]);
        }
        cumtab[6][p] = c;                       // grand totals
    }
    __syncthreads();

    // P5: contribution (both roles)
    const float thr = d + 1.0f;
    const int jidx = (q + S > NBIN) ? NBIN : (q + S);
    const int kidx = (q - S + 1 < 0) ? 0 : (q - S + 1);
    const unsigned P = offs[jidx];     // j-role partners: pos <  P
    const unsigned L = offs[kidx];     // k-role partners: pos >= L
    const int Pwv = (int)(P >> 6), Lwv = (int)(L >> 6);
    const unsigned long long Pmask = (1ull << (P & 63)) - 1ull;
    const unsigned long long Lmask = (1ull << (L & 63)) - 1ull;

    const int4 ri4 = *reinterpret_cast<const int4*>(rank + bi * 4);
    const unsigned rip = (unsigned)ri4.x | ((unsigned)ri4.y << 8) |
                         ((unsigned)ri4.z << 16) | ((unsigned)ri4.w << 24);

    float jacc = 0.f, kacc = 0.f;
    #pragma unroll
    for (int t = 0; t < 4; ++t) {
        const int ri = (int)((rip >> (8 * t)) & 0xFFu);
        const int ro = (int)((rpk >> (8 * t)) & 0xFFu);
        const float wt = wfl[t];
        if (ro > 0 && ro < ri) {                       // j-role
            const int w = t * 4 + (ro - 1);
            const unsigned N = cumtab[Pwv][w] +
                               (unsigned)__popcll(cm[Pwv][w] & Pmask);
            jacc += wt * (float)N;
        }
        if (ro + 1 < ri) {                             // k-role
            const int wh = t * 4 + (ri - 1);
            const int wl = t * 4 + ro;
            const unsigned cLh = cumtab[Lwv][wh] +
                                 (unsigned)__popcll(cm[Lwv][wh] & Lmask);
            const unsigned cLl = cumtab[Lwv][wl] +
                                 (unsigned)__popcll(cm[Lwv][wl] & Lmask);
            const unsigned C = (cumtab[6][wh] - cLh) - (cumtab[6][wl] - cLl);
            kacc += wt * (float)C;
        }
    }
    float contrib = jacc * thr - kacc * d;

    // block reduction
    #pragma unroll
    for (int off = 32; off > 0; off >>= 1)
        contrib += __shfl_down(contrib, off);
    if ((p & 63) == 0) red[wv] = contrib;
    __syncthreads();
    if (p == 0) {
        float s = 0.f;
        #pragma unroll
        for (int w = 0; w < 6; ++w) s += red[w];
        __hip_atomic_store(&partial[bi], __float_as_uint(s),
                           __ATOMIC_RELEASE, __HIP_MEMORY_SCOPE_AGENT);
    }

    // designated block: spin past sentinels (independent slots), fold -> out
    if (bi == NB - 1) {
        __syncthreads();                 // red[] reuse: prior reads complete
        unsigned v;
        do {
            v = __hip_atomic_load(&partial[p], __ATOMIC_ACQUIRE,
                                  __HIP_MEMORY_SCOPE_AGENT);
        } while (v == SENT);
        float val = __uint_as_float(v);
        #pragma unroll
        for (int off = 32; off > 0; off >>= 1)
            val += __shfl_down(val, off);
        if ((p & 63) == 0) red[wv] = val;
        __syncthreads();
        if (p == 0) {
            float s = 0.f;
            #pragma unroll
            for (int w = 0; w < 6; ++w) s += red[w];
            out[0] = s;
        }
    }
}

extern "C" void kernel_launch(void* const* d_in, const int* in_sizes, int n_in,
                              void* d_out, int out_size, void* d_ws, size_t ws_size,
                              hipStream_t stream)
{
    (void)in_sizes; (void)n_in; (void)out_size; (void)ws_size;
    const float* emb  = (const float*)d_in[0];
    const float* tw   = (const float*)d_in[1];
    const int*   rank = (const int*)d_in[2];
    float* ws  = (float*)d_ws;
    float* out = (float*)d_out;

    prep_kernel<<<96, 256, 0, stream>>>(emb, tw, rank, ws);
    loss_kernel<<<NB, NB, 0, stream>>>(
        emb, reinterpret_cast<const uint2*>(ws + ETP_OFF), rank,
        ws + WF_OFF, reinterpret_cast<unsigned*>(ws + PART_OFF), out);
}